// Round 5
// baseline (392.911 us; speedup 1.0000x reference)
//
#include <hip/hip_runtime.h>

// LIF forward recurrence, bit-exact vs the numpy fp32 reference.
//
// Per step (exact op order, correctly-rounded, never FMA-contracted):
//   th   = 1 + 1.5*a
//   v    = (v - v/20) + I_t
//   s    = (v >= th) ? 1 : 0        // STE forward == s_hard exactly (Sterbenz)
//   snum += s                       // s in {0,1} -> exact integer cumsum
//   v    = s ? -0.5 : v
//   a    = (a - a/100) + s          // == s ? (a'+1) : a' with a' = a - a/100
//
// R1: LDS 64x64 tile transpose killed 3x HBM write amplification.
// R2: Markstein 3-op constant division (provably == __fdiv_rn for d=20,100).
// R4: producer/consumer wave specialization (compute wave / helper wave).
// R5 (this): light barriers. __syncthreads() emits s_waitcnt vmcnt(0)
// before s_barrier, which (a) drains the helper's 32 global stores every
// tile (BW-limited serial drain) and (b) drains the compute wave's input
// prefetch every tile. The LDS handoff only needs lgkmcnt(0):
//   - compute's ds_writes retire before barrier (lgkmcnt),
//   - helper's ds_reads complete before its dependent stores issue,
//     so the lag-1 double-buffer WAR is safe without vmcnt.
// Stores become fire-and-forget (drained once at kernel end); prefetch
// loads stay in flight across barriers (compiler waits at use).

#define LIF_L  2048
#define TILE   64
#define NTILES (LIF_L / TILE)   // 32
#define STRIDE 65               // pad: LDS bank = lane%32 / (lane+4c)%32 -> <=2 lanes/bank (free)

__device__ __forceinline__ void barrier_lds_only() {
    asm volatile("s_waitcnt lgkmcnt(0)\n\ts_barrier" ::: "memory");
}

__device__ __forceinline__ float div20(float v) {
    const float rh = 0.05f;                    // rn(1/20)
    float q0 = __fmul_rn(v, rh);
    float r  = __fmaf_rn(-20.0f, q0, v);
    return __fmaf_rn(r, rh, q0);               // == __fdiv_rn(v, 20.0f) for all v
}

__device__ __forceinline__ float div100(float a) {
    const float rh = 0.01f;                    // rn(1/100)
    float q0 = __fmul_rn(a, rh);
    float r  = __fmaf_rn(-100.0f, q0, a);
    return __fmaf_rn(r, rh, q0);               // == __fdiv_rn(a, 100.0f) for all a
}

__device__ __forceinline__ float lif_step(float It, float& v, float& a) {
    float th = __fadd_rn(1.0f, __fmul_rn(1.5f, a));
    float vn = __fadd_rn(__fsub_rn(v, div20(v)), It);
    // a' and a'+1 computed off the critical compare path; select after cmp.
    float ap  = __fsub_rn(a, div100(a));
    float ap1 = __fadd_rn(ap, 1.0f);           // == rn(a' + s) when s==1
    bool fire = (vn >= th);
    v = fire ? -0.5f : vn;
    a = fire ? ap1 : ap;
    return fire ? 1.0f : 0.0f;
}

__global__ __launch_bounds__(128, 1) void lif_fwd(const float* __restrict__ I,
                                                  float* __restrict__ spikes,
                                                  float* __restrict__ series) {
    __shared__ float sp_tile[2][64 * STRIDE];  // double-buffered spike tiles
    __shared__ float se_tile[64 * STRIDE];     // helper-private series tile

    const int tid  = threadIdx.x;
    const int wave = tid >> 6;         // 0 = compute, 1 = helper
    const int lane = tid & 63;
    const int row0 = blockIdx.x * 64;

    // ---- compute-wave state ----
    const float4* __restrict__ I4 =
        reinterpret_cast<const float4*>(I + (size_t)(row0 + lane) * LIF_L);
    float v = 0.0f, a = 0.0f;
    float4 bufA[16], bufB[16];

    // ---- helper-wave state ----
    float carry = 0.0f;                // per-row running spike count (exact int)

    if (wave == 0) {
        #pragma unroll
        for (int i = 0; i < 16; ++i) bufA[i] = I4[i];
        #pragma unroll
        for (int i = 0; i < 16; ++i) bufB[i] = I4[16 + i];
    }

    auto compute_tile = [&](const float4* buf, float* sp) {
        #pragma unroll
        for (int c = 0; c < 16; ++c) {
            float4 in = buf[c];
            float s0 = lif_step(in.x, v, a);
            float s1 = lif_step(in.y, v, a);
            float s2 = lif_step(in.z, v, a);
            float s3 = lif_step(in.w, v, a);
            int b = lane * STRIDE + c * 4;
            sp[b + 0] = s0; sp[b + 1] = s1;
            sp[b + 2] = s2; sp[b + 3] = s3;
        }
    };

    auto helper_tile = [&](int tkt, const float* sp) {
        // 1) per-row cumsum (lane = row): exact {0,1} adds in reference order
        const int rb = lane * STRIDE;
        #pragma unroll
        for (int c = 0; c < 16; ++c) {
            float4 sv = make_float4(sp[rb + c*4], sp[rb + c*4 + 1],
                                    sp[rb + c*4 + 2], sp[rb + c*4 + 3]);
            float4 nv;
            carry = __fadd_rn(carry, sv.x); nv.x = carry;
            carry = __fadd_rn(carry, sv.y); nv.y = carry;
            carry = __fadd_rn(carry, sv.z); nv.z = carry;
            carry = __fadd_rn(carry, sv.w); nv.w = carry;
            se_tile[rb + c*4 + 0] = nv.x; se_tile[rb + c*4 + 1] = nv.y;
            se_tile[rb + c*4 + 2] = nv.z; se_tile[rb + c*4 + 3] = nv.w;
        }
        // 2) transposed coalesced flush: instr i covers 4 rows x 256 B
        const size_t colbase = (size_t)tkt * TILE;
        #pragma unroll
        for (int i = 0; i < 16; ++i) {
            int idx = i * 64 + lane;
            int row = idx >> 4;
            int c4  = (idx & 15) * 4;
            int lb  = row * STRIDE + c4;
            float4 vs = make_float4(sp[lb], sp[lb + 1], sp[lb + 2], sp[lb + 3]);
            float4 ve = make_float4(se_tile[lb], se_tile[lb + 1],
                                    se_tile[lb + 2], se_tile[lb + 3]);
            size_t g = (size_t)(row0 + row) * LIF_L + colbase + c4;
            *reinterpret_cast<float4*>(spikes + g) = vs;
            *reinterpret_cast<float4*>(series + g) = ve;
        }
    };

    for (int kt = 0; kt < NTILES; kt += 2) {
        // tile kt (buffer 0); helper consumes tile kt-1 (buffer 1)
        if (wave == 0) {
            compute_tile(bufA, sp_tile[0]);
            if (kt + 2 < NTILES) {
                #pragma unroll
                for (int i = 0; i < 16; ++i) bufA[i] = I4[(kt + 2) * 16 + i];
            }
        } else if (kt > 0) {
            helper_tile(kt - 1, sp_tile[1]);
        }
        barrier_lds_only();
        // tile kt+1 (buffer 1); helper consumes tile kt (buffer 0)
        if (wave == 0) {
            compute_tile(bufB, sp_tile[1]);
            if (kt + 3 < NTILES) {
                #pragma unroll
                for (int i = 0; i < 16; ++i) bufB[i] = I4[(kt + 3) * 16 + i];
            }
        } else {
            helper_tile(kt, sp_tile[0]);
        }
        barrier_lds_only();
    }
    // tail: last tile (no barrier needed after)
    if (wave == 1) helper_tile(NTILES - 1, sp_tile[1]);
}

extern "C" void kernel_launch(void* const* d_in, const int* in_sizes, int n_in,
                              void* d_out, int out_size, void* d_ws, size_t ws_size,
                              hipStream_t stream) {
    const float* I = (const float*)d_in[0];
    const int B = in_sizes[0] / LIF_L;                  // 16384
    float* spikes = (float*)d_out;                      // (B, L)
    float* series = (float*)d_out + (size_t)B * LIF_L;  // (B, L)

    const int threads = 128;                            // 2 waves: compute + helper
    const int blocks = B / 64;                          // 256 blocks, 64 rows each
    lif_fwd<<<blocks, threads, 0, stream>>>(I, spikes, series);
}

// Round 6
// 382.384 us; speedup vs baseline: 1.0275x; 1.0275x over previous
//
#include <hip/hip_runtime.h>

// LIF forward recurrence, bit-exact vs the numpy fp32 reference.
//
// Reference per step (exact op order, correctly rounded, no contraction):
//   th   = 1 + 1.5*a
//   v    = (v - v/20) + I_t
//   s    = (v >= th) ? 1 : 0        // STE forward == s_hard exactly (Sterbenz)
//   snum += s                       // exact {0,1} integer cumsum
//   v    = s ? -0.5 : v
//   a    = (a - a/100) + s
//
// R1: LDS 64x64 tile transpose killed 3x HBM write amplification.
// R2: Markstein 3-op constant division (provably == __fdiv_rn for d=20,100).
// R4: producer/consumer wave specialization.
// R5: lgkm-only barriers (neutral -> drain wasn't the gate).
// R6 (this):
//  a) XOR-swizzled LDS layout (stride 64, group g stored at g^(row&15)):
//     every LDS access is an aligned b128 at the minimal 8 bank-rows.
//     Helper ds issue drops ~2.4x; compute writes 1 b128 per 4 steps.
//  b) Speculative-decay recurrence on vn (v is never output): both
//     successor values rn(rn(vn-rn(vn/20))+I') and rn(C0+I') computed in
//     parallel with the compare, cndmask after. C0 = rn(-0.5 - rn(-0.5/20))
//     at compile time. Exact reference rounding sequences on both paths.

#define LIF_L  2048
#define TILE   64
#define NTILES (LIF_L / TILE)   // 32

// Compile-time, correctly rounded: rn(-0.5/20) and rn(-0.5 - that).
constexpr float kR20 = -0.5f / 20.0f;
constexpr float kC0  = -0.5f - kR20;

__device__ __forceinline__ void barrier_lds_only() {
    asm volatile("s_waitcnt lgkmcnt(0)\n\ts_barrier" ::: "memory");
}

// One step. vn = membrane AFTER input add (what the threshold sees).
// Inext = input of the NEXT step. Returns spike float {0,1}.
__device__ __forceinline__ float lif_step(float Inext, float& vn, float& a, float& th) {
    bool fire = (vn >= th);
    float s = fire ? 1.0f : 0.0f;
    // no-spike successor: rn(rn(vn - rn(vn/20)) + Inext), Markstein div
    float q0 = __fmul_rn(vn, 0.05f);
    float r  = __fmaf_rn(-20.0f, q0, vn);
    float d  = __fmaf_rn(r, 0.05f, q0);        // == __fdiv_rn(vn, 20) for all vn
    float ns = __fadd_rn(__fsub_rn(vn, d), Inext);
    // spike successor: rn(C0 + Inext)
    float ss = __fadd_rn(kC0, Inext);
    vn = fire ? ss : ns;
    // a: ap = rn(a - rn(a/100)); a' = fire ? rn(ap+1) : ap   (a >= 0 always)
    float qa = __fmul_rn(a, 0.01f);
    float ra = __fmaf_rn(-100.0f, qa, a);
    float da = __fmaf_rn(ra, 0.01f, qa);       // == __fdiv_rn(a, 100) for all a
    float ap  = __fsub_rn(a, da);
    float ap1 = __fadd_rn(ap, 1.0f);
    a = fire ? ap1 : ap;
    th = __fadd_rn(1.0f, __fmul_rn(1.5f, a));  // reference order: mul then add
    return s;
}

// Swizzled LDS float index for (row, 16B-group g): aligned b128, 8-row minimal.
__device__ __forceinline__ int sw_idx(int row, int g) {
    return row * 64 + (((g) ^ (row & 15)) << 2);
}

__global__ __launch_bounds__(128, 1) void lif_fwd(const float* __restrict__ I,
                                                  float* __restrict__ spikes,
                                                  float* __restrict__ series) {
    __shared__ float sp_tile[2][64 * 64];      // double-buffered spike tiles (32 KB)
    __shared__ float se_tile[64 * 64];         // helper-private series tile (16 KB)

    const int tid  = threadIdx.x;
    const int wave = tid >> 6;                 // 0 = compute, 1 = helper
    const int lane = tid & 63;
    const int row0 = blockIdx.x * 64;

    const float4* __restrict__ I4 =
        reinterpret_cast<const float4*>(I + (size_t)(row0 + lane) * LIF_L);

    // compute-wave state
    float vn = 0.0f, a = 0.0f, th = 1.0f;
    float4 bufA[16], bufB[16];
    // helper-wave state
    float carry = 0.0f;

    if (wave == 0) {
        #pragma unroll
        for (int i = 0; i < 16; ++i) bufA[i] = I4[i];
        #pragma unroll
        for (int i = 0; i < 16; ++i) bufB[i] = I4[16 + i];
    }

    auto compute_tile = [&](const float4* buf, float nx0, float* sp) {
        #pragma unroll
        for (int c = 0; c < 16; ++c) {
            float4 in = buf[c];
            float nxt = (c < 15) ? buf[c + 1].x : nx0;
            float4 os;
            os.x = lif_step(in.y, vn, a, th);
            os.y = lif_step(in.z, vn, a, th);
            os.z = lif_step(in.w, vn, a, th);
            os.w = lif_step(nxt,  vn, a, th);
            *reinterpret_cast<float4*>(&sp[sw_idx(lane, c)]) = os;  // ds_write_b128
        }
    };

    auto helper_tile = [&](int tkt, const float* sp) {
        // 1) per-row cumsum (lane = row), b128 reads/writes, exact {0,1} adds
        #pragma unroll
        for (int c = 0; c < 16; ++c) {
            int ix = sw_idx(lane, c);
            float4 sv = *reinterpret_cast<const float4*>(&sp[ix]);
            float4 nv;
            carry = __fadd_rn(carry, sv.x); nv.x = carry;
            carry = __fadd_rn(carry, sv.y); nv.y = carry;
            carry = __fadd_rn(carry, sv.z); nv.z = carry;
            carry = __fadd_rn(carry, sv.w); nv.w = carry;
            *reinterpret_cast<float4*>(&se_tile[ix]) = nv;
        }
        // 2) transposed coalesced flush: instr i covers 4 rows x 256 B
        const size_t colbase = (size_t)tkt * TILE;
        #pragma unroll
        for (int i = 0; i < 16; ++i) {
            int row = i * 4 + (lane >> 4);
            int g   = lane & 15;
            int ix  = sw_idx(row, g);
            float4 vs = *reinterpret_cast<const float4*>(&sp[ix]);
            float4 ve = *reinterpret_cast<const float4*>(&se_tile[ix]);
            size_t gaddr = (size_t)(row0 + row) * LIF_L + colbase + (size_t)g * 4;
            *reinterpret_cast<float4*>(spikes + gaddr) = vs;
            *reinterpret_cast<float4*>(series + gaddr) = ve;
        }
    };

    // init: vn_0 = rn(rn(0 - rn(0/20)) + I_0) = I_0 exactly
    if (wave == 0) vn = bufA[0].x;   // waits only this load's vmcnt

    for (int kt = 0; kt < NTILES; kt += 2) {
        // tile kt (buffer 0); helper consumes tile kt-1 (buffer 1)
        if (wave == 0) {
            compute_tile(bufA, bufB[0].x, sp_tile[0]);
            if (kt + 2 < NTILES) {
                #pragma unroll
                for (int i = 0; i < 16; ++i) bufA[i] = I4[(kt + 2) * 16 + i];
            }
        } else if (kt > 0) {
            helper_tile(kt - 1, sp_tile[1]);
        }
        barrier_lds_only();
        // tile kt+1 (buffer 1); helper consumes tile kt (buffer 0)
        if (wave == 0) {
            // next input for tile kt+1 is tile kt+2's first element (just reloaded
            // into bufA); for the last tile pass 0 (result unused).
            float nx0 = (kt + 2 < NTILES) ? bufA[0].x : 0.0f;
            compute_tile(bufB, nx0, sp_tile[1]);
            if (kt + 3 < NTILES) {
                #pragma unroll
                for (int i = 0; i < 16; ++i) bufB[i] = I4[(kt + 3) * 16 + i];
            }
        } else {
            helper_tile(kt, sp_tile[0]);
        }
        barrier_lds_only();
    }
    // tail: last tile
    if (wave == 1) helper_tile(NTILES - 1, sp_tile[1]);
}

extern "C" void kernel_launch(void* const* d_in, const int* in_sizes, int n_in,
                              void* d_out, int out_size, void* d_ws, size_t ws_size,
                              hipStream_t stream) {
    const float* I = (const float*)d_in[0];
    const int B = in_sizes[0] / LIF_L;                  // 16384
    float* spikes = (float*)d_out;                      // (B, L)
    float* series = (float*)d_out + (size_t)B * LIF_L;  // (B, L)

    const int threads = 128;                            // 2 waves: compute + helper
    const int blocks = B / 64;                          // 256 blocks, 64 rows each
    lif_fwd<<<blocks, threads, 0, stream>>>(I, spikes, series);
}

// Round 7
// 377.183 us; speedup vs baseline: 1.0417x; 1.0138x over previous
//
#include <hip/hip_runtime.h>

// LIF forward recurrence, bit-exact vs the numpy fp32 reference.
//
// Reference per step (exact op order, correctly rounded, no contraction):
//   th   = 1 + 1.5*a
//   v    = (v - v/20) + I_t
//   s    = (v >= th) ? 1 : 0        // STE forward == s_hard exactly (Sterbenz)
//   snum += s                       // exact {0,1} integer cumsum
//   v    = s ? -0.5 : v
//   a    = (a - a/100) + s
//
// R1: LDS 64x64 tile transpose killed 3x HBM write amplification.
// R2: Markstein 3-op constant division (provably == __fdiv_rn for d=20,100).
// R4: producer/consumer wave specialization.
// R5: lgkm-only barriers.
// R6: XOR-swizzled b128 LDS layout + speculative-decay recurrence on vn.
// R7 (this): quad-buffered spike tiles, one barrier per 2 tiles. The
// write stream is the roofline (32 KB/tile/CU vs ~10.4 B/cyc HBM share);
// with 1 barrier/tile, store backpressure on the helper propagates into
// the compute wave every tile. Pair-wise double buffering (4 tile bufs,
// disjoint sets per pair) halves barriers and gives a 2-tile smoothing
// window. LDS 80 KB, still 1 block/CU.

#define LIF_L  2048
#define TILE   64
#define NTILES (LIF_L / TILE)   // 32

// Compile-time, correctly rounded: rn(-0.5/20) and rn(-0.5 - that).
constexpr float kR20 = -0.5f / 20.0f;
constexpr float kC0  = -0.5f - kR20;

__device__ __forceinline__ void barrier_lds_only() {
    asm volatile("s_waitcnt lgkmcnt(0)\n\ts_barrier" ::: "memory");
}

// One step. vn = membrane AFTER input add (what the threshold sees).
// Inext = input of the NEXT step. Returns spike float {0,1}.
__device__ __forceinline__ float lif_step(float Inext, float& vn, float& a, float& th) {
    bool fire = (vn >= th);
    float s = fire ? 1.0f : 0.0f;
    // no-spike successor: rn(rn(vn - rn(vn/20)) + Inext), Markstein div
    float q0 = __fmul_rn(vn, 0.05f);
    float r  = __fmaf_rn(-20.0f, q0, vn);
    float d  = __fmaf_rn(r, 0.05f, q0);        // == __fdiv_rn(vn, 20) for all vn
    float ns = __fadd_rn(__fsub_rn(vn, d), Inext);
    // spike successor: rn(C0 + Inext)
    float ss = __fadd_rn(kC0, Inext);
    vn = fire ? ss : ns;
    // a: ap = rn(a - rn(a/100)); a' = fire ? rn(ap+1) : ap   (a >= 0 always)
    float qa = __fmul_rn(a, 0.01f);
    float ra = __fmaf_rn(-100.0f, qa, a);
    float da = __fmaf_rn(ra, 0.01f, qa);       // == __fdiv_rn(a, 100) for all a
    float ap  = __fsub_rn(a, da);
    float ap1 = __fadd_rn(ap, 1.0f);
    a = fire ? ap1 : ap;
    th = __fadd_rn(1.0f, __fmul_rn(1.5f, a));  // reference order: mul then add
    return s;
}

// Swizzled LDS float index for (row, 16B-group g): aligned b128, conflict-free.
__device__ __forceinline__ int sw_idx(int row, int g) {
    return row * 64 + (((g) ^ (row & 15)) << 2);
}

__global__ __launch_bounds__(128, 1) void lif_fwd(const float* __restrict__ I,
                                                  float* __restrict__ spikes,
                                                  float* __restrict__ series) {
    __shared__ float sp_tile[4][64 * 64];      // quad-buffered spike tiles (64 KB)
    __shared__ float se_tile[64 * 64];         // helper-private series tile (16 KB)

    const int tid  = threadIdx.x;
    const int wave = tid >> 6;                 // 0 = compute, 1 = helper
    const int lane = tid & 63;
    const int row0 = blockIdx.x * 64;

    const float4* __restrict__ I4 =
        reinterpret_cast<const float4*>(I + (size_t)(row0 + lane) * LIF_L);

    // compute-wave state
    float vn = 0.0f, a = 0.0f, th = 1.0f;
    float4 bufA[16], bufB[16];
    // helper-wave state
    float carry = 0.0f;

    if (wave == 0) {
        #pragma unroll
        for (int i = 0; i < 16; ++i) bufA[i] = I4[i];
        #pragma unroll
        for (int i = 0; i < 16; ++i) bufB[i] = I4[16 + i];
    }

    auto compute_tile = [&](const float4* buf, float nx0, float* sp) {
        #pragma unroll
        for (int c = 0; c < 16; ++c) {
            float4 in = buf[c];
            float nxt = (c < 15) ? buf[c + 1].x : nx0;
            float4 os;
            os.x = lif_step(in.y, vn, a, th);
            os.y = lif_step(in.z, vn, a, th);
            os.z = lif_step(in.w, vn, a, th);
            os.w = lif_step(nxt,  vn, a, th);
            *reinterpret_cast<float4*>(&sp[sw_idx(lane, c)]) = os;  // ds_write_b128
        }
    };

    auto helper_tile = [&](int tkt, const float* sp) {
        // 1) per-row cumsum (lane = row), b128 LDS ops, exact {0,1} adds
        #pragma unroll
        for (int c = 0; c < 16; ++c) {
            int ix = sw_idx(lane, c);
            float4 sv = *reinterpret_cast<const float4*>(&sp[ix]);
            float4 nv;
            carry = __fadd_rn(carry, sv.x); nv.x = carry;
            carry = __fadd_rn(carry, sv.y); nv.y = carry;
            carry = __fadd_rn(carry, sv.z); nv.z = carry;
            carry = __fadd_rn(carry, sv.w); nv.w = carry;
            *reinterpret_cast<float4*>(&se_tile[ix]) = nv;
        }
        // 2) transposed coalesced flush: instr i covers 4 rows x 256 B
        const size_t colbase = (size_t)tkt * TILE;
        #pragma unroll
        for (int i = 0; i < 16; ++i) {
            int row = i * 4 + (lane >> 4);
            int g   = lane & 15;
            int ix  = sw_idx(row, g);
            float4 vs = *reinterpret_cast<const float4*>(&sp[ix]);
            float4 ve = *reinterpret_cast<const float4*>(&se_tile[ix]);
            size_t gaddr = (size_t)(row0 + row) * LIF_L + colbase + (size_t)g * 4;
            *reinterpret_cast<float4*>(spikes + gaddr) = vs;
            *reinterpret_cast<float4*>(series + gaddr) = ve;
        }
    };

    // init: vn_0 = rn(rn(0 - rn(0/20)) + I_0) = I_0 exactly
    if (wave == 0) vn = bufA[0].x;

    // Pair loop: iteration p computes tiles {2p, 2p+1} into buffer set
    // {(2p)&3, (2p+1)&3}; helper consumes pair p-1 (the other set).
    // One barrier per pair. WAR across pairs is set-disjoint by parity.
    for (int p = 0; p < NTILES / 2; ++p) {
        const int kt = 2 * p;
        if (wave == 0) {
            compute_tile(bufA, bufB[0].x, sp_tile[kt & 3]);
            if (kt + 2 < NTILES) {
                #pragma unroll
                for (int i = 0; i < 16; ++i) bufA[i] = I4[(kt + 2) * 16 + i];
            }
            float nx0 = (kt + 2 < NTILES) ? bufA[0].x : 0.0f;
            compute_tile(bufB, nx0, sp_tile[(kt + 1) & 3]);
            if (kt + 3 < NTILES) {
                #pragma unroll
                for (int i = 0; i < 16; ++i) bufB[i] = I4[(kt + 3) * 16 + i];
            }
        } else if (p > 0) {
            helper_tile(kt - 2, sp_tile[(kt - 2) & 3]);
            helper_tile(kt - 1, sp_tile[(kt - 1) & 3]);
        }
        barrier_lds_only();
    }
    // tail: last pair
    if (wave == 1) {
        helper_tile(NTILES - 2, sp_tile[(NTILES - 2) & 3]);
        helper_tile(NTILES - 1, sp_tile[(NTILES - 1) & 3]);
    }
}

extern "C" void kernel_launch(void* const* d_in, const int* in_sizes, int n_in,
                              void* d_out, int out_size, void* d_ws, size_t ws_size,
                              hipStream_t stream) {
    const float* I = (const float*)d_in[0];
    const int B = in_sizes[0] / LIF_L;                  // 16384
    float* spikes = (float*)d_out;                      // (B, L)
    float* series = (float*)d_out + (size_t)B * LIF_L;  // (B, L)

    const int threads = 128;                            // 2 waves: compute + helper
    const int blocks = B / 64;                          // 256 blocks, 64 rows each
    lif_fwd<<<blocks, threads, 0, stream>>>(I, spikes, series);
}